// Round 5
// baseline (521.004 us; speedup 1.0000x reference)
//
#include <hip/hip_runtime.h>
#include <hip/hip_bf16.h>

typedef unsigned short u16;
typedef __attribute__((ext_vector_type(8))) short short8;
typedef __attribute__((ext_vector_type(4))) float float4v;
typedef __attribute__((ext_vector_type(16))) float f32x16;
typedef __attribute__((ext_vector_type(2))) int int2v;

__device__ __forceinline__ u16 f2b(float f) {  // RNE f32->bf16 bits (proven)
    unsigned int u = __float_as_uint(f);
    return (u16)((u + 0x7fffu + ((u >> 16) & 1u)) >> 16);
}

__device__ __forceinline__ f32x16 zero16() {
    f32x16 z;
#pragma unroll
    for (int q = 0; q < 16; ++q) z[q] = 0.f;
    return z;
}

#define MFMA32(a, b, c) __builtin_amdgcn_mfma_f32_32x32x16_bf16((a), (b), (c), 0, 0, 0)

// ws (u16): wqk[8][128][128] @0 : wqk[h][ck][c0] = 0.125 * sum_d Wq[c0][h64+d]*Wk[ck][h64+d]
//           wvt[8][64][128] @131072 : Wv_h^T[dv][c]
//           wot[128][512]   @196608 : Wo^T[cout][n]
__global__ void prep_weights(const float* __restrict__ Wq,
                             const float* __restrict__ Wkv,
                             const float* __restrict__ Wo,
                             u16* __restrict__ ws)
{
    const int bid = blockIdx.x, tid = threadIdx.x;
    if (bid < 32) {   // wqk: block = (h, 32-row group g)
        __shared__ float wq_s[128 * 65];
        __shared__ float wk_s[32 * 65];
        const int h = bid >> 2, g = bid & 3;
        for (int i = tid; i < 8192; i += 256) {
            int c0 = i >> 6, d = i & 63;
            wq_s[c0 * 65 + d] = Wq[c0 * 512 + h * 64 + d];
        }
        for (int i = tid; i < 2048; i += 256) {
            int cl = i >> 6, d = i & 63;
            wk_s[cl * 65 + d] = Wkv[(g * 32 + cl) * 1024 + h * 64 + d];
        }
        __syncthreads();
        const int c0 = tid & 127, clb = (tid >> 7) * 16;
        float acc[16];
#pragma unroll
        for (int cc = 0; cc < 16; ++cc) acc[cc] = 0.f;
        for (int d = 0; d < 64; ++d) {
            float a = wq_s[c0 * 65 + d];
#pragma unroll
            for (int cc = 0; cc < 16; ++cc)
                acc[cc] = fmaf(a, wk_s[(clb + cc) * 65 + d], acc[cc]);
        }
#pragma unroll
        for (int cc = 0; cc < 16; ++cc)
            ws[h * 16384 + (g * 32 + clb + cc) * 128 + c0] = f2b(0.125f * acc[cc]);
    } else {
        int idx = (bid - 32) * 256 + tid;
        if (idx < 65536) {                 // wvt
            int h = idx >> 13, c = (idx >> 6) & 127, dv = idx & 63;
            ws[131072 + h * 8192 + dv * 128 + c] =
                f2b(Wkv[c * 1024 + 512 + h * 64 + dv]);
        } else {                           // wot
            int j2 = idx - 65536;
            int cout = j2 >> 9, n = j2 & 511;
            ws[196608 + j2] = f2b(Wo[n * 128 + cout]);
        }
    }
}

// WG = 1024 threads (16 waves), one (b, blk). All MFMAs are 32x32x16 bf16
// (2x FLOPs per operand byte vs 16x16x32 -> ~33% fewer DS b128 reads on the
// per-CU LDS pipe, which is the measured bottleneck).
// LDS (u16 el):
//   s_x  [224][136] @0      x window [pos][c], rows 196..223 zero
//   t_sw [64][136]  @30464  t = x_int @ Wqk_h   ([i][ck])
//   v_sw [64][232]  @39168  v^T[dv][j]
//   p_sw [64][232]  @54016  exp(sim)[i][j]
//   o_sw [64][72]   @68864  o[i][dv]
//   s_part[64][8] f32 @ byte 146944 (col 7 always 0)
//   vmul [224] f32    @ byte 148992
//   Total 149888 B -> 1 WG/CU.
// Fragment math per wave: n5 = lane&31 (row/col), half = lane>>5;
//   A/B-frag = b128 at [idx32][kc*16 + half*8]; C/D reg q ->
//   row = (q&3) + 8*(q>>2) + 4*half, col = n5.
// Per-head wave plan: P1: T 8 waves (2i x 4c0) + V 14 tiles (7j x 2dv);
//   S 14 waves (2i x 7j); PV 4 waves (2i x 2dv, K=224); E 8 waves (2i x 4co).
// Design fits the 64-VGPR allocator cap (acc16 + res16 + streams) - rounds
// 2-4 proved the allocator will not grant more and spills instead.
__global__
__attribute__((amdgpu_flat_work_group_size(1024, 1024), amdgpu_waves_per_eu(4, 4)))
void halo_attn(const float* __restrict__ xg,
               const u16* __restrict__ wqk,
               const u16* __restrict__ wvt,
               const u16* __restrict__ wot,
               const float* __restrict__ bo,
               float* __restrict__ outg)
{
    extern __shared__ u16 lds[];
    u16* s_x  = lds;
    u16* t_sw = lds + 30464;
    u16* v_sw = lds + 39168;
    u16* p_sw = lds + 54016;
    u16* o_sw = lds + 68864;
    float* s_part = (float*)((char*)lds + 146944);
    float* vmul   = (float*)((char*)lds + 148992);

    const int tid  = threadIdx.x;
    const int w    = tid >> 6;
    const int lane = tid & 63;
    const int n5   = lane & 31;
    const int half = lane >> 5;

    // XCD-swizzle: 128 consecutive logical blocks per XCD (halo L2 reuse)
    const int wg = (blockIdx.x >> 3) + (blockIdx.x & 7) * 128;
    const int b   = wg >> 8;
    const int blk = wg & 255;
    const int by = blk >> 4, bx = blk & 15;
    const int y0 = by * 8 - 3, x0 = bx * 8 - 3;
    const bool inb = (by >= 1) && (by <= 14) && (bx >= 1) && (bx <= 14);

    // ---- zero s_x pad rows 196..223 (28*136 u16 = 1904 dwords) ----
    for (int t = tid; t < 1904; t += 1024)
        ((unsigned*)(s_x + 196 * 136))[t] = 0u;
    // ---- zero s_part (64*8 f32; col 7 must stay 0 forever) ----
    if (tid < 512) ((unsigned*)s_part)[tid] = 0u;
    // ---- validity mask table ----
    if (tid < 224) {
        int j = tid;
        float v = 0.f;
        if (j < 196) {
            int wy = j / 14, wx = j - wy * 14;
            if (inb || (((unsigned)(y0 + wy) < 128u) && ((unsigned)(x0 + wx) < 128u)))
                v = 1.f;
        }
        vmul[j] = v;
    }
    // ---- stage x window [pos][c] bf16; lanes map to gx for coalescing ----
    for (int idx = tid; idx < 32768; idx += 1024) {
        int wx = idx & 15, wy = (idx >> 4) & 15, c = idx >> 8;
        if (wx < 14 && wy < 14) {
            int gy = y0 + wy, gx = x0 + wx;
            float val = 0.f;
            if (inb || (((unsigned)gy < 128u) && ((unsigned)gx < 128u)))
                val = xg[((b * 128 + c) * 128 + gy) * 128 + gx];
            s_x[(wy * 14 + wx) * 136 + c] = f2b(val);
        }
    }
    __syncthreads();

    f32x16 res = zero16();

#pragma unroll 1
    for (int h = 0; h < 8; ++h) {
        // ===== Phase 1: T (waves 0..7) + V (14 tiles over waves 8..15, 0..5) =====
        if (w < 8) {
            const int c4 = w >> 1;
            const int i = (w & 1) * 32 + n5;
            const int jq = ((i >> 3) + 3) * 14 + (i & 7) + 3;
            f32x16 acc = zero16();
#pragma unroll
            for (int kc = 0; kc < 8; ++kc) {
                short8 a  = *(const short8*)(s_x + jq * 136 + kc * 16 + half * 8);
                short8 bq = *(const short8*)(wqk + h * 16384 +
                                             (c4 * 32 + n5) * 128 + kc * 16 + half * 8);
                acc = MFMA32(a, bq, acc);
            }
#pragma unroll
            for (int q = 0; q < 16; ++q) {
                int rq = (q & 3) + 8 * (q >> 2) + 4 * half;
                t_sw[((w & 1) * 32 + rq) * 136 + c4 * 32 + n5] = f2b(acc[q]);
            }
        }
        {
            const int vt = (w >= 8) ? (w - 8) : (w < 6 ? 8 + w : -1);
            if (vt >= 0) {
                const int j7 = vt % 7, dv2 = vt / 7;
                f32x16 acc = zero16();
#pragma unroll
                for (int kc = 0; kc < 8; ++kc) {
                    short8 a  = *(const short8*)(s_x + (j7 * 32 + n5) * 136 +
                                                 kc * 16 + half * 8);
                    short8 bv = *(const short8*)(wvt + h * 8192 +
                                                 (dv2 * 32 + n5) * 128 + kc * 16 + half * 8);
                    acc = MFMA32(a, bv, acc);
                }
                // v_sw[dv][j]: lane col dv fixed; rows j consecutive in q&3 -> b64
#pragma unroll
                for (int g = 0; g < 4; ++g) {
                    unsigned lo = (unsigned)f2b(acc[4 * g + 0]) |
                                  ((unsigned)f2b(acc[4 * g + 1]) << 16);
                    unsigned hi = (unsigned)f2b(acc[4 * g + 2]) |
                                  ((unsigned)f2b(acc[4 * g + 3]) << 16);
                    int2v pk; pk[0] = (int)lo; pk[1] = (int)hi;
                    *(int2v*)(v_sw + (dv2 * 32 + n5) * 232 +
                              j7 * 32 + 8 * g + 4 * half) = pk;
                }
            }
        }
        __syncthreads();   // B1: t, v ready

        // ===== Phase S (waves 0..13): sim = t @ x_win^T, exp, row-sums =====
        if (w < 14) {
            const int si = w & 1, j7 = w >> 1;
            f32x16 acc = zero16();
#pragma unroll
            for (int kc = 0; kc < 8; ++kc) {
                short8 ta = *(const short8*)(t_sw + (si * 32 + n5) * 136 +
                                             kc * 16 + half * 8);
                short8 xb = *(const short8*)(s_x + (j7 * 32 + n5) * 136 +
                                             kc * 16 + half * 8);
                acc = MFMA32(ta, xb, acc);
            }
            const int j = j7 * 32 + n5;
            const float vm = vmul[j];   // col j uniform across all 16 regs
#pragma unroll
            for (int q = 0; q < 16; ++q) {
                int rq = (q & 3) + 8 * (q >> 2) + 4 * half;
                // masked entries have acc==0 exactly (zero x rows): expf(0)*0 = 0
                float p = __expf(acc[q]) * vm;
                p_sw[(si * 32 + rq) * 232 + j] = f2b(p);
                acc[q] = p;            // reuse acc regs as lsum
            }
#pragma unroll
            for (int mk = 1; mk < 32; mk <<= 1)
#pragma unroll
                for (int q = 0; q < 16; ++q)
                    acc[q] += __shfl_xor(acc[q], mk, 64);
            if (n5 == 0) {             // lanes 0 and 32: one half each
#pragma unroll
                for (int q = 0; q < 16; ++q) {
                    int rq = (q & 3) + 8 * (q >> 2) + 4 * half;
                    s_part[(si * 32 + rq) * 8 + j7] = acc[q];
                }
            }
        }
        __syncthreads();   // B2: p, partial sums ready

        // ===== Phase PV (waves 0..3): o = p @ v^T (K=224), normalize =====
        if (w < 4) {
            const int pi = w & 1, dv2 = w >> 1;
            f32x16 acc = zero16();
#pragma unroll
            for (int kc = 0; kc < 14; ++kc) {
                short8 pa = *(const short8*)(p_sw + (pi * 32 + n5) * 232 +
                                             kc * 16 + half * 8);
                short8 vb = *(const short8*)(v_sw + (dv2 * 32 + n5) * 232 +
                                             kc * 16 + half * 8);
                acc = MFMA32(pa, vb, acc);
            }
#pragma unroll
            for (int q = 0; q < 16; ++q) {
                int rq = (q & 3) + 8 * (q >> 2) + 4 * half;
                int row = pi * 32 + rq;
                float4v s0 = *(const float4v*)(s_part + row * 8);
                float4v s1 = *(const float4v*)(s_part + row * 8 + 4);
                float ss = ((s0[0] + s0[1]) + (s0[2] + s0[3])) +
                           ((s1[0] + s1[1]) + s1[2]);       // col 7 is 0
                o_sw[row * 72 + dv2 * 32 + n5] = f2b(acc[q] / ss);
            }
        }
        __syncthreads();   // B3: o ready

        // ===== Phase E (waves 0..7): res += o @ Wo_h (no barrier after) =====
        if (w < 8) {
            const int c4 = w >> 1, ei = w & 1;
#pragma unroll
            for (int kc = 0; kc < 4; ++kc) {
                short8 ao = *(const short8*)(o_sw + (ei * 32 + n5) * 72 +
                                             kc * 16 + half * 8);
                short8 bw = *(const short8*)(wot + (c4 * 32 + n5) * 512 + h * 64 +
                                             kc * 16 + half * 8);
                res = MFMA32(ao, bw, res);
            }
        }
    } // heads

    // ---- store fp32 out[b][ch][gy][gx] ----
    if (w < 8) {
        const int c4 = w >> 1, ei = w & 1;
        const int ch = c4 * 32 + n5;
        const float bias = bo[ch];
#pragma unroll
        for (int q = 0; q < 16; ++q) {
            int rq = (q & 3) + 8 * (q >> 2) + 4 * half;
            int i = ei * 32 + rq;
            int gy = by * 8 + (i >> 3), gx = bx * 8 + (i & 7);
            outg[((b * 128 + ch) * 128 + gy) * 128 + gx] = res[q] + bias;
        }
    }
}

extern "C" void kernel_launch(void* const* d_in, const int* in_sizes, int n_in,
                              void* d_out, int out_size, void* d_ws, size_t ws_size,
                              hipStream_t stream) {
    const float* x   = (const float*)d_in[0];
    const float* Wq  = (const float*)d_in[1];
    const float* Wkv = (const float*)d_in[2];
    const float* Wo  = (const float*)d_in[3];
    const float* bo  = (const float*)d_in[4];
    float* out = (float*)d_out;
    u16* ws = (u16*)d_ws;   // needs 512 KB

    prep_weights<<<dim3(544), dim3(256), 0, stream>>>(Wq, Wkv, Wo, ws);

    (void)hipFuncSetAttribute((const void*)halo_attn,
                              hipFuncAttributeMaxDynamicSharedMemorySize, 149888);
    halo_attn<<<dim3(1024), dim3(1024), 149888, stream>>>(
        x, ws, ws + 131072, ws + 196608, bo, out);
}

// Round 6
// 462.693 us; speedup vs baseline: 1.1260x; 1.1260x over previous
//
#include <hip/hip_runtime.h>
#include <hip/hip_bf16.h>

typedef unsigned short u16;
typedef __attribute__((ext_vector_type(8))) short short8;
typedef __attribute__((ext_vector_type(16))) float f32x16;
typedef __attribute__((ext_vector_type(2))) int int2v;

__device__ __forceinline__ u16 f2b(float f) {  // RNE f32->bf16 bits (proven)
    unsigned int u = __float_as_uint(f);
    return (u16)((u + 0x7fffu + ((u >> 16) & 1u)) >> 16);
}

__device__ __forceinline__ f32x16 zero16() {
    f32x16 z;
#pragma unroll
    for (int q = 0; q < 16; ++q) z[q] = 0.f;
    return z;
}

#define MFMA32(a, b, c) __builtin_amdgcn_mfma_f32_32x32x16_bf16((a), (b), (c), 0, 0, 0)

// ws (u16): wqk[8][128][128] @0 : wqk[h][ck][c0] = 0.125 * sum_d Wq[c0][h64+d]*Wk[ck][h64+d]
//           wvt[8][64][128] @131072 : Wv_h^T[dv][c]
//           wot[128][512]   @196608 : Wo^T[cout][n]
__global__ void prep_weights(const float* __restrict__ Wq,
                             const float* __restrict__ Wkv,
                             const float* __restrict__ Wo,
                             u16* __restrict__ ws)
{
    const int bid = blockIdx.x, tid = threadIdx.x;
    if (bid < 32) {   // wqk: block = (h, 32-row group g)
        __shared__ float wq_s[128 * 65];
        __shared__ float wk_s[32 * 65];
        const int h = bid >> 2, g = bid & 3;
        for (int i = tid; i < 8192; i += 256) {
            int c0 = i >> 6, d = i & 63;
            wq_s[c0 * 65 + d] = Wq[c0 * 512 + h * 64 + d];
        }
        for (int i = tid; i < 2048; i += 256) {
            int cl = i >> 6, d = i & 63;
            wk_s[cl * 65 + d] = Wkv[(g * 32 + cl) * 1024 + h * 64 + d];
        }
        __syncthreads();
        const int c0 = tid & 127, clb = (tid >> 7) * 16;
        float acc[16];
#pragma unroll
        for (int cc = 0; cc < 16; ++cc) acc[cc] = 0.f;
        for (int d = 0; d < 64; ++d) {
            float a = wq_s[c0 * 65 + d];
#pragma unroll
            for (int cc = 0; cc < 16; ++cc)
                acc[cc] = fmaf(a, wk_s[(clb + cc) * 65 + d], acc[cc]);
        }
#pragma unroll
        for (int cc = 0; cc < 16; ++cc)
            ws[h * 16384 + (g * 32 + clb + cc) * 128 + c0] = f2b(0.125f * acc[cc]);
    } else {
        int idx = (bid - 32) * 256 + tid;
        if (idx < 65536) {                 // wvt
            int h = idx >> 13, c = (idx >> 6) & 127, dv = idx & 63;
            ws[131072 + h * 8192 + dv * 128 + c] =
                f2b(Wkv[c * 1024 + 512 + h * 64 + dv]);
        } else {                           // wot
            int j2 = idx - 65536;
            int cout = j2 >> 9, n = j2 & 511;
            ws[196608 + j2] = f2b(Wo[n * 128 + cout]);
        }
    }
}

// WG = 512 threads (8 waves), one (b, blk). All MFMAs 32x32x16 bf16.
// LDS (u16 el):
//   s_x  [224][136] @0      x window [pos][c], rows 196..223 zero
//   t_sw [64][136]  @30464  t = x_int @ Wqk_h   ([i][ck])
//   v_sw [64][232]  @39168  v^T[dv][j]
//   p_sw [64][232]  @54016  exp(sim)[i][j]
//   o_sw [64][72]   @68864  o[i][dv]
//   vmul [224] f32  @ byte 146944
//   Total 147840 B -> 1 WG/CU (8 waves = 2/EU).
//
// Round-6 design:
//  * 8 waves x 256-VGPR budget (waves_per_eu(2,2)): each wave CACHES its
//    j-tile's x fragments (xj[8] = 64 VGPR) -> V and S phases read ZERO
//    x bytes from LDS, every head. LDS b128 reads/head: ~816(R0) -> ~320.
//  * Row-sums via MFMA(pa, ones) in PV (extra accumulator chain on already-
//    loaded pa fragments) -> the 80-shuffle/wave S reduce (R5's regression,
//    ~6.7k cy/head on the DS pipe) is GONE. Sums land per-lane in the exact
//    C/D layout the normalize loop uses. s_part eliminated.
// Wave roles: T: w -> (ei=w&1, c4=w>>1). V: w<6 -> j7=w, dv{0,1};
//   w6 -> (6,dv0); w7 -> (6,dv1). S: w<6 -> j7=w, si{0,1}; w6 -> (6,si0);
//   w7 -> (6,si1). PV: w<4 -> (pi=w&1, dv2=w>>1), K=224. E: w -> (ei,c4).
__global__
__attribute__((amdgpu_flat_work_group_size(512, 512), amdgpu_waves_per_eu(2, 2)))
void halo_attn(const float* __restrict__ xg,
               const u16* __restrict__ wqk,
               const u16* __restrict__ wvt,
               const u16* __restrict__ wot,
               const float* __restrict__ bo,
               float* __restrict__ outg)
{
    extern __shared__ u16 lds[];
    u16* s_x  = lds;
    u16* t_sw = lds + 30464;
    u16* v_sw = lds + 39168;
    u16* p_sw = lds + 54016;
    u16* o_sw = lds + 68864;
    float* vmul = (float*)((char*)lds + 146944);

    const int tid  = threadIdx.x;
    const int w    = tid >> 6;
    const int lane = tid & 63;
    const int n5   = lane & 31;
    const int half = lane >> 5;

    // XCD-swizzle: 128 consecutive logical blocks per XCD (halo L2 reuse)
    const int wg = (blockIdx.x >> 3) + (blockIdx.x & 7) * 128;
    const int b   = wg >> 8;
    const int blk = wg & 255;
    const int by = blk >> 4, bx = blk & 15;
    const int y0 = by * 8 - 3, x0 = bx * 8 - 3;
    const bool inb = (by >= 1) && (by <= 14) && (bx >= 1) && (bx <= 14);

    // ---- zero s_x pad rows 196..223 (28*136 u16 = 1904 dwords) ----
    for (int t = tid; t < 1904; t += 512)
        ((unsigned*)(s_x + 196 * 136))[t] = 0u;
    // ---- validity mask table ----
    if (tid < 224) {
        int j = tid;
        float v = 0.f;
        if (j < 196) {
            int wy = j / 14, wx = j - wy * 14;
            if (inb || (((unsigned)(y0 + wy) < 128u) && ((unsigned)(x0 + wx) < 128u)))
                v = 1.f;
        }
        vmul[j] = v;
    }
    // ---- stage x window [pos][c] bf16; lanes map to gx for coalescing ----
    for (int idx = tid; idx < 32768; idx += 512) {
        int wx = idx & 15, wy = (idx >> 4) & 15, c = idx >> 8;
        if (wx < 14 && wy < 14) {
            int gy = y0 + wy, gx = x0 + wx;
            float val = 0.f;
            if (inb || (((unsigned)gy < 128u) && ((unsigned)gx < 128u)))
                val = xg[((b * 128 + c) * 128 + gy) * 128 + gx];
            s_x[(wy * 14 + wx) * 136 + c] = f2b(val);
        }
    }
    __syncthreads();

    // ---- fixed wave roles ----
    const int ei = w & 1, c4 = w >> 1;            // T and E tile
    const int i_t = ei * 32 + n5;
    const int jq  = ((i_t >> 3) + 3) * 14 + (i_t & 7) + 3;
    const int j7  = (w < 6) ? w : 6;              // V/S j-tile
    const bool two = (w < 6);                     // handles both dv / both si
    const int alt = (w == 7) ? 1 : 0;             // single-tile waves: which half

    // ---- cache this wave's j-tile x fragments (reused all 8 heads) ----
    short8 xj[8];   // 64 VGPR
#pragma unroll
    for (int kc = 0; kc < 8; ++kc)
        xj[kc] = *(const short8*)(s_x + (j7 * 32 + n5) * 136 + kc * 16 + half * 8);

    f32x16 res = zero16();
    const short os1 = (short)0x3F80;              // bf16 1.0
    const short8 ones = {os1, os1, os1, os1, os1, os1, os1, os1};

#pragma unroll 1
    for (int h = 0; h < 8; ++h) {
        // ===== Phase 1: T (all 8 waves) then V =====
        {
            f32x16 acc = zero16();
#pragma unroll
            for (int kc = 0; kc < 8; ++kc) {
                short8 a  = *(const short8*)(s_x + jq * 136 + kc * 16 + half * 8);
                short8 bq = *(const short8*)(wqk + h * 16384 +
                                             (c4 * 32 + n5) * 128 + kc * 16 + half * 8);
                acc = MFMA32(a, bq, acc);
            }
#pragma unroll
            for (int q = 0; q < 16; ++q) {
                int rq = (q & 3) + 8 * (q >> 2) + 4 * half;
                t_sw[(ei * 32 + rq) * 136 + c4 * 32 + n5] = f2b(acc[q]);
            }
        }
        {
            // V: chain A = dv2 (alt), chain B = dv2=1 (waves 0..5 only)
            f32x16 va = zero16(), vb2 = zero16();
#pragma unroll
            for (int kc = 0; kc < 8; ++kc) {
                short8 b0 = *(const short8*)(wvt + h * 8192 +
                                             (alt * 32 + n5) * 128 + kc * 16 + half * 8);
                va = MFMA32(xj[kc], b0, va);
                if (two) {
                    short8 b1 = *(const short8*)(wvt + h * 8192 +
                                                 (32 + n5) * 128 + kc * 16 + half * 8);
                    vb2 = MFMA32(xj[kc], b1, vb2);
                }
            }
            // v_sw[dv][j]: lane row = j (n5 of j-tile)?? no: row=dv? -> row dv, col j
            // C/D: col = n5 -> dv... A=xj rows j, B=wvt cols dv => C[j][dv].
            // We store v^T[dv][j]: row dv = col of C (n5-indexed by... ) ->
            // lane holds col dv = ??? C[r=j][c=dv]: lane n5 = dv-col, rows = j.
#pragma unroll
            for (int g = 0; g < 4; ++g) {
                unsigned lo = (unsigned)f2b(va[4 * g + 0]) |
                              ((unsigned)f2b(va[4 * g + 1]) << 16);
                unsigned hi = (unsigned)f2b(va[4 * g + 2]) |
                              ((unsigned)f2b(va[4 * g + 3]) << 16);
                int2v pk; pk[0] = (int)lo; pk[1] = (int)hi;
                *(int2v*)(v_sw + (alt * 32 + n5) * 232 + j7 * 32 + 8 * g + 4 * half) = pk;
            }
            if (two) {
#pragma unroll
                for (int g = 0; g < 4; ++g) {
                    unsigned lo = (unsigned)f2b(vb2[4 * g + 0]) |
                                  ((unsigned)f2b(vb2[4 * g + 1]) << 16);
                    unsigned hi = (unsigned)f2b(vb2[4 * g + 2]) |
                                  ((unsigned)f2b(vb2[4 * g + 3]) << 16);
                    int2v pk; pk[0] = (int)lo; pk[1] = (int)hi;
                    *(int2v*)(v_sw + (32 + n5) * 232 + j7 * 32 + 8 * g + 4 * half) = pk;
                }
            }
        }
        __syncthreads();   // B1: t, v ready

        // ===== Phase S: sim = t @ x^T (x cached), exp, write p =====
        {
            f32x16 sa = zero16(), sb = zero16();
#pragma unroll
            for (int kc = 0; kc < 8; ++kc) {
                short8 t0 = *(const short8*)(t_sw + (alt * 32 + n5) * 136 +
                                             kc * 16 + half * 8);
                sa = MFMA32(t0, xj[kc], sa);
                if (two) {
                    short8 t1 = *(const short8*)(t_sw + (32 + n5) * 136 +
                                                 kc * 16 + half * 8);
                    sb = MFMA32(t1, xj[kc], sb);
                }
            }
            const int j = j7 * 32 + n5;
            const float vm = vmul[j];
#pragma unroll
            for (int q = 0; q < 16; ++q) {
                int rq = (q & 3) + 8 * (q >> 2) + 4 * half;
                // masked: sim==0 exactly (zero x rows) -> expf(0)*0 = 0
                float p = __expf(sa[q]) * vm;
                p_sw[(alt * 32 + rq) * 232 + j] = f2b(p);
            }
            if (two) {
#pragma unroll
                for (int q = 0; q < 16; ++q) {
                    int rq = (q & 3) + 8 * (q >> 2) + 4 * half;
                    float p = __expf(sb[q]) * vm;
                    p_sw[(32 + rq) * 232 + j] = f2b(p);
                }
            }
        }
        __syncthreads();   // B2: p ready

        // ===== Phase PV (waves 0..3): o = p @ v^T, s via MFMA(pa, ones) =====
        if (w < 4) {
            const int pi = w & 1, dv2 = w >> 1;
            f32x16 acc = zero16(), accs = zero16();
#pragma unroll
            for (int kc = 0; kc < 14; ++kc) {
                short8 pa = *(const short8*)(p_sw + (pi * 32 + n5) * 232 +
                                             kc * 16 + half * 8);
                short8 vb = *(const short8*)(v_sw + (dv2 * 32 + n5) * 232 +
                                             kc * 16 + half * 8);
                acc  = MFMA32(pa, vb, acc);
                accs = MFMA32(pa, ones, accs);   // row-sums, same layout as acc
            }
#pragma unroll
            for (int q = 0; q < 16; ++q) {
                int rq = (q & 3) + 8 * (q >> 2) + 4 * half;
                int row = pi * 32 + rq;
                o_sw[row * 72 + dv2 * 32 + n5] = f2b(acc[q] / accs[q]);
            }
        }
        __syncthreads();   // B3: o ready

        // ===== Phase E (all 8 waves): res += o @ Wo_h (no barrier after) =====
        {
#pragma unroll
            for (int kc = 0; kc < 4; ++kc) {
                short8 ao = *(const short8*)(o_sw + (ei * 32 + n5) * 72 +
                                             kc * 16 + half * 8);
                short8 bw = *(const short8*)(wot + (c4 * 32 + n5) * 512 + h * 64 +
                                             kc * 16 + half * 8);
                res = MFMA32(ao, bw, res);
            }
        }
    } // heads

    // ---- store fp32 out[b][ch][gy][gx] ----
    {
        const int ch = c4 * 32 + n5;
        const float bias = bo[ch];
#pragma unroll
        for (int q = 0; q < 16; ++q) {
            int rq = (q & 3) + 8 * (q >> 2) + 4 * half;
            int i = ei * 32 + rq;
            int gy = by * 8 + (i >> 3), gx = bx * 8 + (i & 7);
            outg[((b * 128 + ch) * 128 + gy) * 128 + gx] = res[q] + bias;
        }
    }
}

extern "C" void kernel_launch(void* const* d_in, const int* in_sizes, int n_in,
                              void* d_out, int out_size, void* d_ws, size_t ws_size,
                              hipStream_t stream) {
    const float* x   = (const float*)d_in[0];
    const float* Wq  = (const float*)d_in[1];
    const float* Wkv = (const float*)d_in[2];
    const float* Wo  = (const float*)d_in[3];
    const float* bo  = (const float*)d_in[4];
    float* out = (float*)d_out;
    u16* ws = (u16*)d_ws;   // needs 512 KB

    prep_weights<<<dim3(544), dim3(256), 0, stream>>>(Wq, Wkv, Wo, ws);

    (void)hipFuncSetAttribute((const void*)halo_attn,
                              hipFuncAttributeMaxDynamicSharedMemorySize, 147840);
    halo_attn<<<dim3(1024), dim3(512), 147840, stream>>>(
        x, ws, ws + 131072, ws + 196608, bo, out);
}